// Round 1
// baseline (5461.395 us; speedup 1.0000x reference)
//
#include <hip/hip_runtime.h>
#include <math.h>

#define N_ROWS 8192
#define D_DIM  2048
#define K_CODES 10000
#define EPSF   1e-12f
#define KSPLIT 8
#define KCHUNK 1250   // K_CODES / KSPLIT

#define BM 64
#define BN 64
#define BD 32

// ---------------- ws layout (float offsets) ----------------
#define OFF_XSQ   0
#define OFF_XINV  (OFF_XSQ  + N_ROWS)            // 8192
#define OFF_WSQ   (OFF_XINV + N_ROWS)            // 16384
#define OFF_WINV  (OFF_WSQ  + K_CODES)           // 26384
#define OFF_PDIST (OFF_WINV + K_CODES)           // 36384
#define OFF_PIDX  (OFF_PDIST + KSPLIT * N_ROWS)  // 101920
#define OFF_IDX   (OFF_PIDX  + KSPLIT * N_ROWS)  // 167456
#define OFF_LP    (OFF_IDX   + N_ROWS)           // 175648

__device__ __forceinline__ float block_reduce_sum(float v) {
  #pragma unroll
  for (int o = 32; o > 0; o >>= 1) v += __shfl_down(v, o, 64);
  __shared__ float ls[4];
  int lane = threadIdx.x & 63;
  int wid  = threadIdx.x >> 6;
  if (lane == 0) ls[wid] = v;
  __syncthreads();
  v = (threadIdx.x < 4) ? ls[threadIdx.x] : 0.0f;
  if (wid == 0) {
    v += __shfl_down(v, 2, 64);
    v += __shfl_down(v, 1, 64);
  }
  __syncthreads();   // make back-to-back calls safe
  return v;          // valid in thread 0
}

// One block per row: compute inv_norm = 1/max(||row||,eps) and
// sq = sum((row*inv)^2)  (mirrors reference: normalize then sum of squares)
__global__ __launch_bounds__(256) void norm_kernel(const float* __restrict__ src,
                                                   float* __restrict__ sq_out,
                                                   float* __restrict__ inv_out) {
  int row = blockIdx.x;
  const float4* p = (const float4*)(src + (size_t)row * D_DIM);
  int tid = threadIdx.x;
  float4 v0 = p[tid];
  float4 v1 = p[tid + 256];
  float s = v0.x*v0.x + v0.y*v0.y + v0.z*v0.z + v0.w*v0.w
          + v1.x*v1.x + v1.y*v1.y + v1.z*v1.z + v1.w*v1.w;
  s = block_reduce_sum(s);
  __shared__ float sh_inv;
  if (tid == 0) sh_inv = 1.0f / fmaxf(sqrtf(s), EPSF);
  __syncthreads();
  float inv = sh_inv;
  float t = 0.0f, nv;
  nv = v0.x*inv; t += nv*nv;
  nv = v0.y*inv; t += nv*nv;
  nv = v0.z*inv; t += nv*nv;
  nv = v0.w*inv; t += nv*nv;
  nv = v1.x*inv; t += nv*nv;
  nv = v1.y*inv; t += nv*nv;
  nv = v1.z*inv; t += nv*nv;
  nv = v1.w*inv; t += nv*nv;
  t = block_reduce_sum(t);
  if (tid == 0) { sq_out[row] = t; inv_out[row] = inv; }
}

// Tiled fp32 GEMM (xn . wn^T) fused with per-row argmin over this block's k-range.
// grid = (N/BM, KSPLIT), block = 256 (16x16, 4x4 micro-tile)
__global__ __launch_bounds__(256) void dist_argmin_kernel(
    const float* __restrict__ x, const float* __restrict__ w,
    const float* __restrict__ xsq, const float* __restrict__ xinv,
    const float* __restrict__ wsq, const float* __restrict__ winv,
    float* __restrict__ pdist, int* __restrict__ pidx)
{
  __shared__ float as[BD][BM + 4];
  __shared__ float bs[BD][BN + 4];
  __shared__ float rd[BM][16];
  __shared__ int   rix[BM][16];

  int tid = threadIdx.x;
  int tx = tid & 15, ty = tid >> 4;
  int row0 = blockIdx.x * BM;
  int kbeg = blockIdx.y * KCHUNK;
  int kend = min(K_CODES, kbeg + KCHUNK);

  float xs_r[4];
  #pragma unroll
  for (int i = 0; i < 4; ++i) xs_r[i] = xsq[row0 + ty * 4 + i];

  float best[4];
  int   bidx[4];
  #pragma unroll
  for (int i = 0; i < 4; ++i) { best[i] = INFINITY; bidx[i] = 0x7fffffff; }

  int lm  = tid >> 2;        // 0..63 : row (for A) / col (for B) within tile
  int ldo = (tid & 3) * 8;   // 0,8,16,24 : d offset
  const float* xrow = x + (size_t)(row0 + lm) * D_DIM;
  float xim = xinv[row0 + lm];

  for (int t = kbeg; t < kend; t += BN) {
    float acc[4][4];
    #pragma unroll
    for (int i = 0; i < 4; ++i)
      #pragma unroll
      for (int j = 0; j < 4; ++j) acc[i][j] = 0.0f;

    int wc = t + lm;
    bool wvalid = (wc < kend);
    const float* wrow = w + (size_t)(wvalid ? wc : 0) * D_DIM;
    float wim = wvalid ? winv[wc] : 0.0f;

    for (int d0 = 0; d0 < D_DIM; d0 += BD) {
      float4 a0 = *(const float4*)(xrow + d0 + ldo);
      float4 a1 = *(const float4*)(xrow + d0 + ldo + 4);
      float4 b0 = *(const float4*)(wrow + d0 + ldo);
      float4 b1 = *(const float4*)(wrow + d0 + ldo + 4);
      as[ldo + 0][lm] = a0.x * xim;
      as[ldo + 1][lm] = a0.y * xim;
      as[ldo + 2][lm] = a0.z * xim;
      as[ldo + 3][lm] = a0.w * xim;
      as[ldo + 4][lm] = a1.x * xim;
      as[ldo + 5][lm] = a1.y * xim;
      as[ldo + 6][lm] = a1.z * xim;
      as[ldo + 7][lm] = a1.w * xim;
      bs[ldo + 0][lm] = b0.x * wim;
      bs[ldo + 1][lm] = b0.y * wim;
      bs[ldo + 2][lm] = b0.z * wim;
      bs[ldo + 3][lm] = b0.w * wim;
      bs[ldo + 4][lm] = b1.x * wim;
      bs[ldo + 5][lm] = b1.y * wim;
      bs[ldo + 6][lm] = b1.z * wim;
      bs[ldo + 7][lm] = b1.w * wim;
      __syncthreads();
      #pragma unroll
      for (int d = 0; d < BD; ++d) {
        float4 av = *(const float4*)(&as[d][ty * 4]);
        float4 bv = *(const float4*)(&bs[d][tx * 4]);
        float a[4] = {av.x, av.y, av.z, av.w};
        float b[4] = {bv.x, bv.y, bv.z, bv.w};
        #pragma unroll
        for (int i = 0; i < 4; ++i)
          #pragma unroll
          for (int j = 0; j < 4; ++j) acc[i][j] += a[i] * b[j];
      }
      __syncthreads();
    }

    // argmin update for this k-tile (k ascending => strict < keeps first occurrence)
    #pragma unroll
    for (int j = 0; j < 4; ++j) {
      int c = t + tx * 4 + j;
      if (c < kend) {
        float wsq_c = wsq[c];
        #pragma unroll
        for (int i = 0; i < 4; ++i) {
          float dist = (xs_r[i] + wsq_c) - 2.0f * acc[i][j];
          if (dist < best[i]) { best[i] = dist; bidx[i] = c; }
        }
      }
    }
  }

  // cross-thread (over tx) argmin per row
  #pragma unroll
  for (int i = 0; i < 4; ++i) {
    rd [ty * 4 + i][tx] = best[i];
    rix[ty * 4 + i][tx] = bidx[i];
  }
  __syncthreads();
  if (tid < BM) {
    float b = rd[tid][0];
    int  bi = rix[tid][0];
    #pragma unroll
    for (int t2 = 1; t2 < 16; ++t2) {
      float d = rd[tid][t2];
      int  ix = rix[tid][t2];
      if (d < b || (d == b && ix < bi)) { b = d; bi = ix; }
    }
    pdist[blockIdx.y * N_ROWS + row0 + tid] = b;
    pidx [blockIdx.y * N_ROWS + row0 + tid] = bi;
  }
}

// Reduce KSPLIT partials per row; write int idx (for gather) and float idx (output 2)
__global__ __launch_bounds__(256) void argmin_reduce_kernel(
    const float* __restrict__ pdist, const int* __restrict__ pidx,
    int* __restrict__ idx_out, float* __restrict__ idxf_out)
{
  int row = blockIdx.x * 256 + threadIdx.x;
  if (row >= N_ROWS) return;
  float b = INFINITY; int bi = 0x7fffffff;
  #pragma unroll
  for (int s = 0; s < KSPLIT; ++s) {
    float d = pdist[s * N_ROWS + row];
    int  ix = pidx [s * N_ROWS + row];
    if (d < b || (d == b && ix < bi)) { b = d; bi = ix; }
  }
  idx_out[row]  = bi;
  idxf_out[row] = (float)bi;
}

// quantized = weight[idx]; per-row partial sum of (q-x)^2
__global__ __launch_bounds__(256) void gather_kernel(
    const float* __restrict__ x, const float* __restrict__ w,
    const int* __restrict__ idx, float* __restrict__ out,
    float* __restrict__ lpart)
{
  int row = blockIdx.x;
  int tid = threadIdx.x;
  int id = idx[row];
  const float4* wr = (const float4*)(w + (size_t)id * D_DIM);
  const float4* xr = (const float4*)(x + (size_t)row * D_DIM);
  float4* outr = (float4*)(out + (size_t)row * D_DIM);
  float s = 0.0f;
  #pragma unroll
  for (int t = 0; t < 2; ++t) {
    int e = tid + t * 256;
    float4 wv = wr[e], xv = xr[e];
    outr[e] = wv;
    float d0 = wv.x - xv.x, d1 = wv.y - xv.y, d2 = wv.z - xv.z, d3 = wv.w - xv.w;
    s += d0 * d0 + d1 * d1 + d2 * d2 + d3 * d3;
  }
  s = block_reduce_sum(s);
  if (tid == 0) lpart[row] = s;
}

// deterministic final loss reduce (double accumulation, fixed order)
__global__ __launch_bounds__(256) void loss_kernel(const float* __restrict__ lpart,
                                                   float* __restrict__ loss_out)
{
  int tid = threadIdx.x;
  double s = 0.0;
  for (int t = tid; t < N_ROWS; t += 256) s += (double)lpart[t];
  __shared__ double sd[256];
  sd[tid] = s;
  __syncthreads();
  #pragma unroll
  for (int o = 128; o > 0; o >>= 1) {
    if (tid < o) sd[tid] += sd[tid + o];
    __syncthreads();
  }
  if (tid == 0)
    loss_out[0] = (float)(1.25 * sd[0] / (double)((size_t)N_ROWS * (size_t)D_DIM));
}

extern "C" void kernel_launch(void* const* d_in, const int* in_sizes, int n_in,
                              void* d_out, int out_size, void* d_ws, size_t ws_size,
                              hipStream_t stream) {
  const float* x = (const float*)d_in[0];
  const float* w = (const float*)d_in[1];
  float* out = (float*)d_out;
  float* ws  = (float*)d_ws;

  float* xsq   = ws + OFF_XSQ;
  float* xinv  = ws + OFF_XINV;
  float* wsq   = ws + OFF_WSQ;
  float* winv  = ws + OFF_WINV;
  float* pdist = ws + OFF_PDIST;
  int*   pidx  = (int*)(ws + OFF_PIDX);
  int*   idx   = (int*)(ws + OFF_IDX);
  float* lpart = ws + OFF_LP;

  float* q_out    = out;                                   // N*D
  float* loss_out = out + (size_t)N_ROWS * D_DIM;          // 1
  float* idxf_out = out + (size_t)N_ROWS * D_DIM + 1;      // N

  norm_kernel<<<N_ROWS, 256, 0, stream>>>(x, xsq, xinv);
  norm_kernel<<<K_CODES, 256, 0, stream>>>(w, wsq, winv);
  dist_argmin_kernel<<<dim3(N_ROWS / BM, KSPLIT), 256, 0, stream>>>(
      x, w, xsq, xinv, wsq, winv, pdist, pidx);
  argmin_reduce_kernel<<<(N_ROWS + 255) / 256, 256, 0, stream>>>(
      pdist, pidx, idx, idxf_out);
  gather_kernel<<<N_ROWS, 256, 0, stream>>>(x, w, idx, out, lpart);
  loss_kernel<<<1, 256, 0, stream>>>(lpart, loss_out);
}

// Round 2
// 1092.133 us; speedup vs baseline: 5.0007x; 5.0007x over previous
//
#include <hip/hip_runtime.h>
#include <math.h>

#define N_ROWS 8192
#define D_DIM  2048
#define K_CODES 10000
#define EPSF   1e-12f

#define BM 128
#define BN 128
#define NCT 79            // ceil(10000/128)

typedef short short8 __attribute__((ext_vector_type(8)));
typedef float f32x4  __attribute__((ext_vector_type(4)));

__device__ __forceinline__ unsigned short f2bf(float f) {
  unsigned u = __float_as_uint(f);
  unsigned r = (u + 0x7fffu + ((u >> 16) & 1u)) >> 16;   // RNE
  return (unsigned short)r;
}
__device__ __forceinline__ float bf2f(unsigned short h) {
  return __uint_as_float(((unsigned)h) << 16);
}

__device__ __forceinline__ void stage16(const unsigned short* g, unsigned short* l) {
  __builtin_amdgcn_global_load_lds(
      (const __attribute__((address_space(1))) unsigned int*)g,
      (__attribute__((address_space(3))) unsigned int*)l, 16, 0, 0);
}

__device__ __forceinline__ float block_reduce_sum(float v) {
  #pragma unroll
  for (int o = 32; o > 0; o >>= 1) v += __shfl_down(v, o, 64);
  __shared__ float ls[4];
  int lane = threadIdx.x & 63;
  int wid  = threadIdx.x >> 6;
  if (lane == 0) ls[wid] = v;
  __syncthreads();
  v = (threadIdx.x < 4) ? ls[threadIdx.x] : 0.0f;
  if (wid == 0) {
    v += __shfl_down(v, 2, 64);
    v += __shfl_down(v, 1, 64);
  }
  __syncthreads();
  return v;   // valid in thread 0
}

// One block per row: normalize, split into bf16 hi/lo, store sq = sum(xn^2)
__global__ __launch_bounds__(256) void norm_split_kernel(
    const float* __restrict__ src,
    unsigned short* __restrict__ hi, unsigned short* __restrict__ lo,
    float* __restrict__ sq_out)
{
  int row = blockIdx.x;
  int tid = threadIdx.x;
  const float* rp = src + (size_t)row * D_DIM;
  float4 v0 = *(const float4*)(rp + tid * 8);
  float4 v1 = *(const float4*)(rp + tid * 8 + 4);
  float s = v0.x*v0.x + v0.y*v0.y + v0.z*v0.z + v0.w*v0.w
          + v1.x*v1.x + v1.y*v1.y + v1.z*v1.z + v1.w*v1.w;
  s = block_reduce_sum(s);
  __shared__ float sh_inv;
  if (tid == 0) sh_inv = 1.0f / fmaxf(sqrtf(s), EPSF);
  __syncthreads();
  float inv = sh_inv;

  float xs[8] = {v0.x, v0.y, v0.z, v0.w, v1.x, v1.y, v1.z, v1.w};
  unsigned short hb[8], lb[8];
  float t = 0.0f;
  #pragma unroll
  for (int i = 0; i < 8; ++i) {
    float xn = xs[i] * inv;
    t += xn * xn;
    unsigned short h = f2bf(xn);
    hb[i] = h;
    lb[i] = f2bf(xn - bf2f(h));
  }
  *(short8*)(hi + (size_t)row * D_DIM + tid * 8) = *(short8*)hb;
  *(short8*)(lo + (size_t)row * D_DIM + tid * 8) = *(short8*)lb;
  t = block_reduce_sum(t);
  if (tid == 0) sq_out[row] = t;
}

// MFMA distance + fused per-row argmin over this block's 128 codes.
// grid = (N/128, NCT), block = 256 (4 waves, 2x2 wave grid, 64x64 per wave)
__global__ __launch_bounds__(256) void dist_argmin_kernel(
    const unsigned short* __restrict__ xh, const unsigned short* __restrict__ xl,
    const unsigned short* __restrict__ wh, const unsigned short* __restrict__ wl,
    const float* __restrict__ wsq,
    float* __restrict__ pdist, int* __restrict__ pidx)
{
  __shared__ unsigned short lAh[128 * 32], lAl[128 * 32];
  __shared__ unsigned short lBh[128 * 32], lBl[128 * 32];
  __shared__ float redd[128][2];
  __shared__ int   redi[128][2];

  const int tid  = threadIdx.x;
  const int lane = tid & 63;
  const int wv   = tid >> 6;          // wave 0..3
  const int wm   = wv >> 1;           // wave row 0..1
  const int wn   = wv & 1;            // wave col 0..1
  const int t16  = lane & 15;
  const int h    = lane >> 4;         // 0..3
  const int ko   = h * 8;             // k offset within 32

  const int row0  = blockIdx.x * BM;
  const int kbase = blockIdx.y * BN;

  // staging geometry: each wave fills 2 sections (16 rows) per tile
  const int srow  = lane >> 2;        // 0..15
  const int kslot = lane & 3;         // 16B slot (8 bf16)

  const int ra0 = row0 + wv * 32 + srow;
  const int ra1 = ra0 + 16;
  int rbq0 = kbase + wv * 32 + srow;
  int rbq1 = rbq0 + 16;
  const int rb0 = rbq0 < K_CODES ? rbq0 : K_CODES - 1;
  const int rb1 = rbq1 < K_CODES ? rbq1 : K_CODES - 1;

  const unsigned short* pah0 = xh + (size_t)ra0 * D_DIM + kslot * 8;
  const unsigned short* pah1 = xh + (size_t)ra1 * D_DIM + kslot * 8;
  const unsigned short* pal0 = xl + (size_t)ra0 * D_DIM + kslot * 8;
  const unsigned short* pal1 = xl + (size_t)ra1 * D_DIM + kslot * 8;
  const unsigned short* pbh0 = wh + (size_t)rb0 * D_DIM + kslot * 8;
  const unsigned short* pbh1 = wh + (size_t)rb1 * D_DIM + kslot * 8;
  const unsigned short* pbl0 = wl + (size_t)rb0 * D_DIM + kslot * 8;
  const unsigned short* pbl1 = wl + (size_t)rb1 * D_DIM + kslot * 8;

  unsigned short* dA0 = lAh + wv * 1024;
  unsigned short* dA1 = lAh + wv * 1024 + 512;
  unsigned short* dAl0 = lAl + wv * 1024;
  unsigned short* dAl1 = lAl + wv * 1024 + 512;
  unsigned short* dB0 = lBh + wv * 1024;
  unsigned short* dB1 = lBh + wv * 1024 + 512;
  unsigned short* dBl0 = lBl + wv * 1024;
  unsigned short* dBl1 = lBl + wv * 1024 + 512;

  f32x4 acc[4][4];
  #pragma unroll
  for (int m = 0; m < 4; ++m)
    #pragma unroll
    for (int n = 0; n < 4; ++n) acc[m][n] = (f32x4){0.f, 0.f, 0.f, 0.f};

  const int arow = wm * 64 + t16;
  const int bcol = wn * 64 + t16;

  for (int kt = 0; kt < D_DIM / 32; ++kt) {
    const int koff = kt * 32;
    stage16(pah0 + koff, dA0);
    stage16(pah1 + koff, dA1);
    stage16(pal0 + koff, dAl0);
    stage16(pal1 + koff, dAl1);
    stage16(pbh0 + koff, dB0);
    stage16(pbh1 + koff, dB1);
    stage16(pbl0 + koff, dBl0);
    stage16(pbl1 + koff, dBl1);
    __syncthreads();

    short8 ah[4], al[4], bh[4], bl[4];
    #pragma unroll
    for (int m = 0; m < 4; ++m) {
      ah[m] = *(const short8*)(lAh + (arow + m * 16) * 32 + ko);
      al[m] = *(const short8*)(lAl + (arow + m * 16) * 32 + ko);
    }
    #pragma unroll
    for (int n = 0; n < 4; ++n) {
      bh[n] = *(const short8*)(lBh + (bcol + n * 16) * 32 + ko);
      bl[n] = *(const short8*)(lBl + (bcol + n * 16) * 32 + ko);
    }
    #pragma unroll
    for (int m = 0; m < 4; ++m)
      #pragma unroll
      for (int n = 0; n < 4; ++n) {
        acc[m][n] = __builtin_amdgcn_mfma_f32_16x16x32_bf16(ah[m], bh[n], acc[m][n], 0, 0, 0);
        acc[m][n] = __builtin_amdgcn_mfma_f32_16x16x32_bf16(al[m], bh[n], acc[m][n], 0, 0, 0);
        acc[m][n] = __builtin_amdgcn_mfma_f32_16x16x32_bf16(ah[m], bl[n], acc[m][n], 0, 0, 0);
      }
    __syncthreads();
  }

  // epilogue: dist = wsq[c] - 2*dot  (xsq is row-constant -> argmin-invariant)
  float wsq_r[4];
  #pragma unroll
  for (int n = 0; n < 4; ++n) {
    int c = kbase + wn * 64 + n * 16 + t16;
    wsq_r[n] = (c < K_CODES) ? wsq[c] : 0.0f;
  }

  #pragma unroll
  for (int m = 0; m < 4; ++m) {
    #pragma unroll
    for (int r = 0; r < 4; ++r) {
      int rowl = wm * 64 + m * 16 + h * 4 + r;
      float bd = INFINITY;
      int bi = 0x7fffffff;
      #pragma unroll
      for (int n = 0; n < 4; ++n) {
        int c = kbase + wn * 64 + n * 16 + t16;
        float dist = (c < K_CODES) ? (wsq_r[n] - 2.0f * acc[m][n][r]) : INFINITY;
        if (dist < bd) { bd = dist; bi = c; }
      }
      #pragma unroll
      for (int off = 1; off < 16; off <<= 1) {
        float od = __shfl_xor(bd, off, 64);
        int   oi = __shfl_xor(bi, off, 64);
        if (od < bd || (od == bd && oi < bi)) { bd = od; bi = oi; }
      }
      if (t16 == 0) { redd[rowl][wn] = bd; redi[rowl][wn] = bi; }
    }
  }
  __syncthreads();
  if (tid < 128) {
    float d0 = redd[tid][0], d1 = redd[tid][1];
    int   i0 = redi[tid][0], i1 = redi[tid][1];
    bool take1 = (d1 < d0) || (d1 == d0 && i1 < i0);
    pdist[(size_t)blockIdx.y * N_ROWS + row0 + tid] = take1 ? d1 : d0;
    pidx [(size_t)blockIdx.y * N_ROWS + row0 + tid] = take1 ? i1 : i0;
  }
}

__global__ __launch_bounds__(256) void argmin_reduce_kernel(
    const float* __restrict__ pdist, const int* __restrict__ pidx,
    int* __restrict__ idx_out, float* __restrict__ idxf_out)
{
  int row = blockIdx.x * 256 + threadIdx.x;
  if (row >= N_ROWS) return;
  float b = INFINITY; int bi = 0x7fffffff;
  for (int s = 0; s < NCT; ++s) {
    float d = pdist[(size_t)s * N_ROWS + row];
    int  ix = pidx [(size_t)s * N_ROWS + row];
    if (d < b || (d == b && ix < bi)) { b = d; bi = ix; }
  }
  idx_out[row]  = bi;
  idxf_out[row] = (float)bi;
}

__global__ __launch_bounds__(256) void gather_kernel(
    const float* __restrict__ x, const float* __restrict__ w,
    const int* __restrict__ idx, float* __restrict__ out,
    float* __restrict__ lpart)
{
  int row = blockIdx.x;
  int tid = threadIdx.x;
  int id = idx[row];
  const float4* wr = (const float4*)(w + (size_t)id * D_DIM);
  const float4* xr = (const float4*)(x + (size_t)row * D_DIM);
  float4* outr = (float4*)(out + (size_t)row * D_DIM);
  float s = 0.0f;
  #pragma unroll
  for (int t = 0; t < 2; ++t) {
    int e = tid + t * 256;
    float4 wv = wr[e], xv = xr[e];
    outr[e] = wv;
    float d0 = wv.x - xv.x, d1 = wv.y - xv.y, d2 = wv.z - xv.z, d3 = wv.w - xv.w;
    s += d0 * d0 + d1 * d1 + d2 * d2 + d3 * d3;
  }
  s = block_reduce_sum(s);
  if (tid == 0) lpart[row] = s;
}

__global__ __launch_bounds__(256) void loss_kernel(const float* __restrict__ lpart,
                                                   float* __restrict__ loss_out)
{
  int tid = threadIdx.x;
  double s = 0.0;
  for (int t = tid; t < N_ROWS; t += 256) s += (double)lpart[t];
  __shared__ double sd[256];
  sd[tid] = s;
  __syncthreads();
  #pragma unroll
  for (int o = 128; o > 0; o >>= 1) {
    if (tid < o) sd[tid] += sd[tid + o];
    __syncthreads();
  }
  if (tid == 0)
    loss_out[0] = (float)(1.25 * sd[0] / (double)((size_t)N_ROWS * (size_t)D_DIM));
}

extern "C" void kernel_launch(void* const* d_in, const int* in_sizes, int n_in,
                              void* d_out, int out_size, void* d_ws, size_t ws_size,
                              hipStream_t stream) {
  const float* x = (const float*)d_in[0];
  const float* w = (const float*)d_in[1];
  float* out = (float*)d_out;
  char*  ws  = (char*)d_ws;

  size_t off = 0;
  auto alloc = [&](size_t bytes) {
    size_t o = off;
    off = (off + bytes + 255) & ~(size_t)255;
    return o;
  };
  unsigned short* whp = (unsigned short*)(ws + alloc((size_t)K_CODES * D_DIM * 2));
  unsigned short* wlp = (unsigned short*)(ws + alloc((size_t)K_CODES * D_DIM * 2));
  float* wsq   = (float*)(ws + alloc((size_t)K_CODES * 4));
  float* xsq   = (float*)(ws + alloc((size_t)N_ROWS * 4));
  float* pdist = (float*)(ws + alloc((size_t)NCT * N_ROWS * 4));
  int*   pidx  = (int*)  (ws + alloc((size_t)NCT * N_ROWS * 4));
  int*   idx   = (int*)  (ws + alloc((size_t)N_ROWS * 4));
  float* lpart = (float*)(ws + alloc((size_t)N_ROWS * 4));

  unsigned short* xhp;
  unsigned short* xlp;
  size_t xbytes = (size_t)N_ROWS * D_DIM * 2;
  if (ws_size >= off + 2 * xbytes) {
    xhp = (unsigned short*)(ws + alloc(xbytes));
    xlp = (unsigned short*)(ws + alloc(xbytes));
  } else {
    // scratch inside d_out's quantized region (exactly N*D*4 bytes);
    // consumed by dist kernel, then overwritten by gather_kernel (stream-ordered)
    xhp = (unsigned short*)out;
    xlp = xhp + (size_t)N_ROWS * D_DIM;
  }

  float* loss_out = out + (size_t)N_ROWS * D_DIM;
  float* idxf_out = loss_out + 1;

  norm_split_kernel<<<N_ROWS, 256, 0, stream>>>(x, xhp, xlp, xsq);
  norm_split_kernel<<<K_CODES, 256, 0, stream>>>(w, whp, wlp, wsq);
  dist_argmin_kernel<<<dim3(N_ROWS / BM, NCT), 256, 0, stream>>>(
      xhp, xlp, whp, wlp, wsq, pdist, pidx);
  argmin_reduce_kernel<<<(N_ROWS + 255) / 256, 256, 0, stream>>>(
      pdist, pidx, idx, idxf_out);
  gather_kernel<<<N_ROWS, 256, 0, stream>>>(x, w, idx, out, lpart);
  loss_kernel<<<1, 256, 0, stream>>>(lpart, loss_out);
}